// Round 2
// baseline (5638.750 us; speedup 1.0000x reference)
//
#include <hip/hip_runtime.h>
#include <hip/hip_bf16.h>
#include <stdint.h>
#include <math.h>

#define NN 50000
#define DD 128
#define EE 500000

typedef __attribute__((ext_vector_type(8))) short bfx8;   // 8 bf16 = 4 VGPR
typedef __attribute__((ext_vector_type(4))) short bfx4;
typedef __attribute__((ext_vector_type(4))) float f32x4;

static __device__ __forceinline__ short f2bf(float f) {
  union { float f; uint32_t u; } v; v.f = f;
  uint32_t r = (v.u + 0x7fffu + ((v.u >> 16) & 1u)) >> 16;
  return (short)r;
}
static __device__ __forceinline__ float bf2f(short b) {
  union { uint32_t u; float f; } v; v.u = ((uint32_t)(uint16_t)b) << 16;
  return v.f;
}

// ---- fragment loaders: A and B both stored [rows][K=128] K-contiguous ----
// lane l: row = row0 + (l&15), k = k0 + (l>>4)*8 .. +8  (16B contiguous load)
static __device__ __forceinline__ bfx8 load_frag(const short* base, int row0, int k0, int lane) {
  int r = row0 + (lane & 15);
  int k = k0 + ((lane >> 4) << 3);
  return *reinterpret_cast<const bfx8*>(base + (size_t)r * DD + k);
}
static __device__ __forceinline__ bfx8 load_frag_clamp(const short* base, int row0, int k0, int lane) {
  int r = row0 + (lane & 15);
  if (r >= NN) r = NN - 1;                     // tail tile: garbage rows, stores guarded
  int k = k0 + ((lane >> 4) << 3);
  return *reinterpret_cast<const bfx8*>(base + (size_t)r * DD + k);
}
static __device__ __forceinline__ bfx8 load_frag_f32(const float* base, int row0, int k0, int lane) {
  int r = row0 + (lane & 15);
  if (r >= NN) r = NN - 1;
  int k = k0 + ((lane >> 4) << 3);
  const float* p = base + (size_t)r * DD + k;
  f32x4 u = *reinterpret_cast<const f32x4*>(p);
  f32x4 v = *reinterpret_cast<const f32x4*>(p + 4);
  bfx8 o;
  o[0]=f2bf(u[0]); o[1]=f2bf(u[1]); o[2]=f2bf(u[2]); o[3]=f2bf(u[3]);
  o[4]=f2bf(v[0]); o[5]=f2bf(v[1]); o[6]=f2bf(v[2]); o[7]=f2bf(v[3]);
  return o;
}

// ---------------- convert fp32 -> bf16 (x_a, x_b, 12 weight mats) ----------------
struct ConvJobs { const float* src[14]; short* dst[14]; int n[14]; };

__global__ __launch_bounds__(256) void k_convert(ConvJobs jobs) {
  int j = blockIdx.y;
  const float* s = jobs.src[j];
  short* d = jobs.dst[j];
  int n = jobs.n[j];
  int i = (blockIdx.x * 256 + threadIdx.x) * 4;
  if (i >= n) return;
  f32x4 v = *reinterpret_cast<const f32x4*>(s + i);
  bfx4 o;
  o[0]=f2bf(v[0]); o[1]=f2bf(v[1]); o[2]=f2bf(v[2]); o[3]=f2bf(v[3]);
  *reinterpret_cast<bfx4*>(d + i) = o;
}

// ---------------- OUT[N,128] = X[N,128] @ W[128,128]^T  (bf16 out) ----------------
struct GemmJob { const short* X; const short* W; short* out; };
struct GemmJobs2 { GemmJob j[2]; };

__global__ __launch_bounds__(256) void k_gemm(GemmJobs2 jobs) {
  const int wave = threadIdx.x >> 6, lane = threadIdx.x & 63;
  const GemmJob jb = jobs.j[blockIdx.z];
  const int rbase = (blockIdx.x * 4 + wave) * 32;
  if (rbase >= NN) return;
  f32x4 acc[2][8];
  #pragma unroll
  for (int a = 0; a < 2; ++a)
    #pragma unroll
    for (int c = 0; c < 8; ++c) acc[a][c] = (f32x4)(0.f);
  #pragma unroll
  for (int ks = 0; ks < 4; ++ks) {
    const int k0 = ks * 32;
    bfx8 a0 = load_frag_clamp(jb.X, rbase,      k0, lane);
    bfx8 a1 = load_frag_clamp(jb.X, rbase + 16, k0, lane);
    #pragma unroll
    for (int c = 0; c < 8; ++c) {
      bfx8 b = load_frag(jb.W, c * 16, k0, lane);
      acc[0][c] = __builtin_amdgcn_mfma_f32_16x16x32_bf16(a0, b, acc[0][c], 0, 0, 0);
      acc[1][c] = __builtin_amdgcn_mfma_f32_16x16x32_bf16(a1, b, acc[1][c], 0, 0, 0);
    }
  }
  const int col = lane & 15, rsub = (lane >> 4) << 2;
  #pragma unroll
  for (int rf = 0; rf < 2; ++rf)
    #pragma unroll
    for (int c = 0; c < 8; ++c)
      #pragma unroll
      for (int q = 0; q < 4; ++q) {
        int r = rbase + rf * 16 + rsub + q;
        if (r < NN) jb.out[(size_t)r * DD + c * 16 + col] = f2bf(acc[rf][c][q]);
      }
}

// ---------------- scatter: agg[tgt] += sx[src] (f32 atomics) ----------------
__global__ __launch_bounds__(256) void k_scatter(const int* __restrict__ edge,
                                                 const short* __restrict__ sx,
                                                 float* __restrict__ agg) {
  int tid = blockIdx.x * 256 + threadIdx.x;
  int e = tid >> 4, c = tid & 15;
  int s = edge[e];
  int t = edge[EE + e];
  bfx8 v = *reinterpret_cast<const bfx8*>(sx + (size_t)s * DD + c * 8);
  float* dst = agg + (size_t)t * DD + c * 8;
  #pragma unroll
  for (int i = 0; i < 8; ++i) unsafeAtomicAdd(dst + i, bf2f(v[i]));
}

// ---------------- fused GRU: gi=tx@wih^T, gh=agg@whh^T, gates, out ----------------
struct GruArgs {
  const short* tx; const float* agg; const short* wih; const short* whh;
  const float* bih; const float* bhh; float* out; int mode;
};

__global__ __launch_bounds__(256) void k_gru(GruArgs a) {
  const int wave = threadIdx.x >> 6, lane = threadIdx.x & 63;
  const int rbase = blockIdx.x * 32;
  const int dbase = (blockIdx.y * 4 + wave) * 16;   // 8 col-tiles over d=0..127
  f32x4 ai[2][3], ah[2][3];
  #pragma unroll
  for (int rf = 0; rf < 2; ++rf)
    #pragma unroll
    for (int g = 0; g < 3; ++g) { ai[rf][g] = (f32x4)(0.f); ah[rf][g] = (f32x4)(0.f); }
  #pragma unroll
  for (int ks = 0; ks < 4; ++ks) {
    const int k0 = ks * 32;
    bfx8 atx0 = load_frag_clamp(a.tx, rbase,      k0, lane);
    bfx8 atx1 = load_frag_clamp(a.tx, rbase + 16, k0, lane);
    bfx8 ag0  = load_frag_f32(a.agg, rbase,      k0, lane);
    bfx8 ag1  = load_frag_f32(a.agg, rbase + 16, k0, lane);
    #pragma unroll
    for (int g = 0; g < 3; ++g) {
      bfx8 bi = load_frag(a.wih, g * 128 + dbase, k0, lane);
      bfx8 bh = load_frag(a.whh, g * 128 + dbase, k0, lane);
      ai[0][g] = __builtin_amdgcn_mfma_f32_16x16x32_bf16(atx0, bi, ai[0][g], 0, 0, 0);
      ai[1][g] = __builtin_amdgcn_mfma_f32_16x16x32_bf16(atx1, bi, ai[1][g], 0, 0, 0);
      ah[0][g] = __builtin_amdgcn_mfma_f32_16x16x32_bf16(ag0,  bh, ah[0][g], 0, 0, 0);
      ah[1][g] = __builtin_amdgcn_mfma_f32_16x16x32_bf16(ag1,  bh, ah[1][g], 0, 0, 0);
    }
  }
  const int col = dbase + (lane & 15);
  const float bir = a.bih[col], biz = a.bih[128 + col], bin = a.bih[256 + col];
  const float bhr = a.bhh[col], bhz = a.bhh[128 + col], bhn = a.bhh[256 + col];
  #pragma unroll
  for (int rf = 0; rf < 2; ++rf)
    #pragma unroll
    for (int q = 0; q < 4; ++q) {
      int r = rbase + rf * 16 + ((lane >> 4) << 2) + q;
      if (r >= NN) continue;
      float ir = ai[rf][0][q] + bir, iz = ai[rf][1][q] + biz, in = ai[rf][2][q] + bin;
      float hr = ah[rf][0][q] + bhr, hz = ah[rf][1][q] + bhz, hn = ah[rf][2][q] + bhn;
      float rr = 1.f / (1.f + expf(-(ir + hr)));
      float zz = 1.f / (1.f + expf(-(iz + hz)));
      float nn = tanhf(in + rr * hn);
      float h  = a.agg[(size_t)r * DD + col];
      float res = (1.f - zz) * nn + zz * h;
      size_t o = (size_t)r * DD + col;
      if (a.mode == 0)      a.out[o] = fmaxf(res, 0.f);
      else if (a.mode == 1) a.out[o] = res;
      else                  a.out[o] = fmaxf((a.out[o] + res) * 0.5f, 0.f);
    }
}

extern "C" void kernel_launch(void* const* d_in, const int* in_sizes, int n_in,
                              void* d_out, int out_size, void* d_ws, size_t ws_size,
                              hipStream_t stream) {
  const float* x_a = (const float*)d_in[0];
  const float* x_b = (const float*)d_in[1];
  const int* edges[3] = {(const int*)d_in[2], (const int*)d_in[3], (const int*)d_in[4]};
  const float *Ws[3], *Wt[3], *wih[3], *whh[3], *bih[3], *bhh[3];
  for (int e = 0; e < 3; ++e) {
    int b = 5 + e * 6;
    Ws[e]  = (const float*)d_in[b + 0];
    Wt[e]  = (const float*)d_in[b + 1];
    wih[e] = (const float*)d_in[b + 2];
    whh[e] = (const float*)d_in[b + 3];
    bih[e] = (const float*)d_in[b + 4];
    bhh[e] = (const float*)d_in[b + 5];
  }

  // workspace layout (sequential edge processing; ~77.6 MB total)
  char* ws = (char*)d_ws;
  float* agg   = (float*)ws;                     // 25.6 MB
  short* xa_bf = (short*)(ws + 25600000);        // 12.8 MB
  short* xb_bf = (short*)(ws + 38400000);        // 12.8 MB
  short* sx_bf = (short*)(ws + 51200000);        // 12.8 MB
  short* tx_bf = (short*)(ws + 64000000);        // 12.8 MB
  short* wbf   = (short*)(ws + 76800000);        // 786 KB
  short *Wsb[3], *Wtb[3], *wihb[3], *whhb[3];
  for (int e = 0; e < 3; ++e) {
    short* base = wbf + (size_t)e * 131072;
    Wsb[e] = base; Wtb[e] = base + 16384; wihb[e] = base + 32768; whhb[e] = base + 81920;
  }

  // 1) convert everything to bf16
  ConvJobs cj;
  cj.src[0] = x_a; cj.dst[0] = xa_bf; cj.n[0] = NN * DD;
  cj.src[1] = x_b; cj.dst[1] = xb_bf; cj.n[1] = NN * DD;
  for (int e = 0; e < 3; ++e) {
    cj.src[2+e*4+0] = Ws[e];  cj.dst[2+e*4+0] = Wsb[e];  cj.n[2+e*4+0] = 16384;
    cj.src[2+e*4+1] = Wt[e];  cj.dst[2+e*4+1] = Wtb[e];  cj.n[2+e*4+1] = 16384;
    cj.src[2+e*4+2] = wih[e]; cj.dst[2+e*4+2] = wihb[e]; cj.n[2+e*4+2] = 49152;
    cj.src[2+e*4+3] = whh[e]; cj.dst[2+e*4+3] = whhb[e]; cj.n[2+e*4+3] = 49152;
  }
  hipLaunchKernelGGL(k_convert, dim3(6250, 14), dim3(256), 0, stream, cj);

  float* out_a = (float*)d_out;
  float* out_b = (float*)d_out + (size_t)NN * DD;
  const int ROWT = (NN + 31) / 32;               // 1563
  const int GEMM_BX = (ROWT + 3) / 4;            // 391

  // edge configs: {src_bf, tgt_bf, edge_idx, out, mode}
  const short* srcb[3] = {xa_bf, xb_bf, xb_bf};
  const short* tgtb[3] = {xb_bf, xa_bf, xa_bf};
  float* outp[3] = {out_b, out_a, out_a};
  int mode[3] = {0, 1, 2};

  for (int e = 0; e < 3; ++e) {
    (void)hipMemsetAsync(agg, 0, (size_t)NN * DD * sizeof(float), stream);
    GemmJobs2 gj;
    gj.j[0] = {srcb[e], Wsb[e], sx_bf};
    gj.j[1] = {tgtb[e], Wtb[e], tx_bf};
    hipLaunchKernelGGL(k_gemm, dim3(GEMM_BX, 1, 2), dim3(256), 0, stream, gj);
    hipLaunchKernelGGL(k_scatter, dim3(EE * 16 / 256), dim3(256), 0, stream,
                       edges[e], (const short*)sx_bf, agg);
    GruArgs ga = {tx_bf, agg, wihb[e], whhb[e], bih[e], bhh[e], outp[e], mode[e]};
    hipLaunchKernelGGL(k_gru, dim3(ROWT, 2), dim3(256), 0, stream, ga);
  }
}

// Round 3
// 857.406 us; speedup vs baseline: 6.5765x; 6.5765x over previous
//
#include <hip/hip_runtime.h>
#include <hip/hip_bf16.h>
#include <stdint.h>
#include <math.h>

#define NN 50000
#define DD 128
#define EE 500000

typedef __attribute__((ext_vector_type(8))) short bfx8;   // 8 bf16 = 4 VGPR
typedef __attribute__((ext_vector_type(4))) short bfx4;
typedef __attribute__((ext_vector_type(4))) float f32x4;

static __device__ __forceinline__ short f2bf(float f) {
  union { float f; uint32_t u; } v; v.f = f;
  uint32_t r = (v.u + 0x7fffu + ((v.u >> 16) & 1u)) >> 16;
  return (short)r;
}
static __device__ __forceinline__ float bf2f(short b) {
  union { uint32_t u; float f; } v; v.u = ((uint32_t)(uint16_t)b) << 16;
  return v.f;
}

// ---- fragment loaders: A and B both stored [rows][K=128] K-contiguous ----
static __device__ __forceinline__ bfx8 load_frag(const short* base, int row0, int k0, int lane) {
  int r = row0 + (lane & 15);
  int k = k0 + ((lane >> 4) << 3);
  return *reinterpret_cast<const bfx8*>(base + (size_t)r * DD + k);
}
static __device__ __forceinline__ bfx8 load_frag_clamp(const short* base, int row0, int k0, int lane) {
  int r = row0 + (lane & 15);
  if (r >= NN) r = NN - 1;
  int k = k0 + ((lane >> 4) << 3);
  return *reinterpret_cast<const bfx8*>(base + (size_t)r * DD + k);
}
static __device__ __forceinline__ bfx8 load_frag_f32(const float* base, int row0, int k0, int lane) {
  int r = row0 + (lane & 15);
  if (r >= NN) r = NN - 1;
  int k = k0 + ((lane >> 4) << 3);
  const float* p = base + (size_t)r * DD + k;
  f32x4 u = *reinterpret_cast<const f32x4*>(p);
  f32x4 v = *reinterpret_cast<const f32x4*>(p + 4);
  bfx8 o;
  o[0]=f2bf(u[0]); o[1]=f2bf(u[1]); o[2]=f2bf(u[2]); o[3]=f2bf(u[3]);
  o[4]=f2bf(v[0]); o[5]=f2bf(v[1]); o[6]=f2bf(v[2]); o[7]=f2bf(v[3]);
  return o;
}

// ---------------- convert fp32 -> bf16 (x_a, x_b, Ws x3, whh x3) ----------------
struct ConvJobs { const float* src[8]; short* dst[8]; int n[8]; };

__global__ __launch_bounds__(256) void k_convert(ConvJobs jobs) {
  int j = blockIdx.y;
  const float* s = jobs.src[j];
  short* d = jobs.dst[j];
  int n = jobs.n[j];
  int i = (blockIdx.x * 256 + threadIdx.x) * 4;
  if (i >= n) return;
  f32x4 v = *reinterpret_cast<const f32x4*>(s + i);
  bfx4 o;
  o[0]=f2bf(v[0]); o[1]=f2bf(v[1]); o[2]=f2bf(v[2]); o[3]=f2bf(v[3]);
  *reinterpret_cast<bfx4*>(d + i) = o;
}

// ---------------- comb = wih @ Wt  (f32 accum -> bf16), [384,128] ----------------
struct CombJobs { const float* wih[3]; const float* wt[3]; short* out[3]; };

__global__ __launch_bounds__(256) void k_comb(CombJobs cj) {
  int e = blockIdx.y;
  const float* wih = cj.wih[e];
  const float* wt  = cj.wt[e];
  short* out = cj.out[e];
  int tid = blockIdx.x * 256 + threadIdx.x;   // 49152 total
  int i = tid >> 7, j = tid & 127;
  float acc = 0.f;
  #pragma unroll 4
  for (int k = 0; k < 128; ++k) acc += wih[i * 128 + k] * wt[k * 128 + j];
  out[i * 128 + j] = f2bf(acc);
}

// ---------------- sx = X @ Ws^T (bf16 out) ----------------
__global__ __launch_bounds__(256) void k_gemm(const short* __restrict__ X,
                                              const short* __restrict__ W,
                                              short* __restrict__ out) {
  const int wave = threadIdx.x >> 6, lane = threadIdx.x & 63;
  const int rbase = (blockIdx.x * 4 + wave) * 32;
  if (rbase >= NN) return;
  f32x4 acc[2][8];
  #pragma unroll
  for (int a = 0; a < 2; ++a)
    #pragma unroll
    for (int c = 0; c < 8; ++c) acc[a][c] = (f32x4)(0.f);
  #pragma unroll
  for (int ks = 0; ks < 4; ++ks) {
    const int k0 = ks * 32;
    bfx8 a0 = load_frag_clamp(X, rbase,      k0, lane);
    bfx8 a1 = load_frag_clamp(X, rbase + 16, k0, lane);
    #pragma unroll
    for (int c = 0; c < 8; ++c) {
      bfx8 b = load_frag(W, c * 16, k0, lane);
      acc[0][c] = __builtin_amdgcn_mfma_f32_16x16x32_bf16(a0, b, acc[0][c], 0, 0, 0);
      acc[1][c] = __builtin_amdgcn_mfma_f32_16x16x32_bf16(a1, b, acc[1][c], 0, 0, 0);
    }
  }
  const int col = lane & 15, rsub = (lane >> 4) << 2;
  #pragma unroll
  for (int rf = 0; rf < 2; ++rf)
    #pragma unroll
    for (int c = 0; c < 8; ++c)
      #pragma unroll
      for (int q = 0; q < 4; ++q) {
        int r = rbase + rf * 16 + rsub + q;
        if (r < NN) out[(size_t)r * DD + c * 16 + col] = f2bf(acc[rf][c][q]);
      }
}

// ---------------- CSR build ----------------
__global__ __launch_bounds__(256) void k_hist(const int* __restrict__ edge, int* __restrict__ counts) {
  int tid = blockIdx.x * 256 + threadIdx.x;
  if (tid >= EE) return;
  atomicAdd(&counts[edge[EE + tid]], 1);
}

__global__ __launch_bounds__(1024) void k_scan(const int* __restrict__ counts, int* __restrict__ offs) {
  __shared__ int lds[1024];
  __shared__ int carry;
  if (threadIdx.x == 0) carry = 0;
  __syncthreads();
  for (int base = 0; base < NN; base += 1024) {
    int i = base + (int)threadIdx.x;
    int v = (i < NN) ? counts[i] : 0;
    lds[threadIdx.x] = v;
    __syncthreads();
    for (int off = 1; off < 1024; off <<= 1) {
      int t = (threadIdx.x >= (unsigned)off) ? lds[threadIdx.x - off] : 0;
      __syncthreads();
      lds[threadIdx.x] += t;
      __syncthreads();
    }
    int incl = lds[threadIdx.x];
    if (i < NN) offs[i] = carry + incl - v;   // exclusive
    __syncthreads();
    if (threadIdx.x == 1023) carry += lds[1023];
    __syncthreads();
  }
}

// fill: offs[t] atomically advances; afterwards offs[t] == end of row t
__global__ __launch_bounds__(256) void k_fill(const int* __restrict__ edge,
                                              int* __restrict__ offs,
                                              int* __restrict__ bucket) {
  int tid = blockIdx.x * 256 + threadIdx.x;
  if (tid >= EE) return;
  int t = edge[EE + tid];
  int s = edge[tid];
  int pos = atomicAdd(&offs[t], 1);
  bucket[pos] = s;
}

// ---------------- gather-sum: agg[r] = sum over incoming sx rows ----------------
__global__ __launch_bounds__(256) void k_agg(const int* __restrict__ offs,
                                             const int* __restrict__ bucket,
                                             const short* __restrict__ sx,
                                             float* __restrict__ agg) {
  int wave = threadIdx.x >> 6, lane = threadIdx.x & 63;
  int row = (blockIdx.x * 4 + wave) * 2 + (lane >> 5);
  if (row >= NN) return;
  int cl = (lane & 31) * 4;
  int start = row ? offs[row - 1] : 0;
  int end = offs[row];
  f32x4 acc = (f32x4)(0.f);
  for (int i = start; i < end; ++i) {
    int s = bucket[i];
    bfx4 v = *reinterpret_cast<const bfx4*>(sx + (size_t)s * DD + cl);
    acc[0] += bf2f(v[0]); acc[1] += bf2f(v[1]);
    acc[2] += bf2f(v[2]); acc[3] += bf2f(v[3]);
  }
  *reinterpret_cast<f32x4*>(agg + (size_t)row * DD + cl) = acc;
}

// ---------------- fused GRU: gi=xt@comb^T, gh=agg@whh^T, gates, out ----------------
struct GruArgs {
  const short* xt; const float* agg; const short* comb; const short* whh;
  const float* bih; const float* bhh; float* out; int mode;
};

__global__ __launch_bounds__(256) void k_gru(GruArgs a) {
  const int wave = threadIdx.x >> 6, lane = threadIdx.x & 63;
  const int rbase = blockIdx.x * 32;
  const int dbase = (blockIdx.y * 4 + wave) * 16;
  f32x4 ai[2][3], ah[2][3];
  #pragma unroll
  for (int rf = 0; rf < 2; ++rf)
    #pragma unroll
    for (int g = 0; g < 3; ++g) { ai[rf][g] = (f32x4)(0.f); ah[rf][g] = (f32x4)(0.f); }
  #pragma unroll
  for (int ks = 0; ks < 4; ++ks) {
    const int k0 = ks * 32;
    bfx8 axt0 = load_frag_clamp(a.xt, rbase,      k0, lane);
    bfx8 axt1 = load_frag_clamp(a.xt, rbase + 16, k0, lane);
    bfx8 ag0  = load_frag_f32(a.agg, rbase,      k0, lane);
    bfx8 ag1  = load_frag_f32(a.agg, rbase + 16, k0, lane);
    #pragma unroll
    for (int g = 0; g < 3; ++g) {
      bfx8 bi = load_frag(a.comb, g * 128 + dbase, k0, lane);
      bfx8 bh = load_frag(a.whh,  g * 128 + dbase, k0, lane);
      ai[0][g] = __builtin_amdgcn_mfma_f32_16x16x32_bf16(axt0, bi, ai[0][g], 0, 0, 0);
      ai[1][g] = __builtin_amdgcn_mfma_f32_16x16x32_bf16(axt1, bi, ai[1][g], 0, 0, 0);
      ah[0][g] = __builtin_amdgcn_mfma_f32_16x16x32_bf16(ag0,  bh, ah[0][g], 0, 0, 0);
      ah[1][g] = __builtin_amdgcn_mfma_f32_16x16x32_bf16(ag1,  bh, ah[1][g], 0, 0, 0);
    }
  }
  const int col = dbase + (lane & 15);
  const float bir = a.bih[col], biz = a.bih[128 + col], bin = a.bih[256 + col];
  const float bhr = a.bhh[col], bhz = a.bhh[128 + col], bhn = a.bhh[256 + col];
  #pragma unroll
  for (int rf = 0; rf < 2; ++rf)
    #pragma unroll
    for (int q = 0; q < 4; ++q) {
      int r = rbase + rf * 16 + ((lane >> 4) << 2) + q;
      if (r >= NN) continue;
      float ir = ai[rf][0][q] + bir, iz = ai[rf][1][q] + biz, in = ai[rf][2][q] + bin;
      float hr = ah[rf][0][q] + bhr, hz = ah[rf][1][q] + bhz, hn = ah[rf][2][q] + bhn;
      float rr = 1.f / (1.f + expf(-(ir + hr)));
      float zz = 1.f / (1.f + expf(-(iz + hz)));
      float nn = tanhf(in + rr * hn);
      float h  = a.agg[(size_t)r * DD + col];
      float res = (1.f - zz) * nn + zz * h;
      size_t o = (size_t)r * DD + col;
      if (a.mode == 0)      a.out[o] = fmaxf(res, 0.f);
      else if (a.mode == 1) a.out[o] = res;
      else                  a.out[o] = fmaxf((a.out[o] + res) * 0.5f, 0.f);
    }
}

extern "C" void kernel_launch(void* const* d_in, const int* in_sizes, int n_in,
                              void* d_out, int out_size, void* d_ws, size_t ws_size,
                              hipStream_t stream) {
  const float* x_a = (const float*)d_in[0];
  const float* x_b = (const float*)d_in[1];
  const int* edges[3] = {(const int*)d_in[2], (const int*)d_in[3], (const int*)d_in[4]};
  const float *Ws[3], *Wt[3], *wih[3], *whh[3], *bih[3], *bhh[3];
  for (int e = 0; e < 3; ++e) {
    int b = 5 + e * 6;
    Ws[e]  = (const float*)d_in[b + 0];
    Wt[e]  = (const float*)d_in[b + 1];
    wih[e] = (const float*)d_in[b + 2];
    whh[e] = (const float*)d_in[b + 3];
    bih[e] = (const float*)d_in[b + 4];
    bhh[e] = (const float*)d_in[b + 5];
  }

  // workspace layout (~67 MB)
  char* ws = (char*)d_ws;
  float* agg   = (float*)ws;                        // 25.6 MB
  short* xa_bf = (short*)(ws + 25600000);           // 12.8 MB
  short* xb_bf = (short*)(ws + 38400000);           // 12.8 MB
  short* sx_bf = (short*)(ws + 51200000);           // 12.8 MB
  int*   counts = (int*)(ws + 64000000);            // 200 KB
  int*   offs   = (int*)(ws + 64200000);            // 200 KB
  int*   bucket = (int*)(ws + 64400000);            // 2 MB
  short* wbf    = (short*)(ws + 66400000);          // 3 * 229 KB
  short *Wsb[3], *combb[3], *whhb[3];
  for (int e = 0; e < 3; ++e) {
    short* base = wbf + (size_t)e * 114688;
    Wsb[e] = base; combb[e] = base + 16384; whhb[e] = base + 65536;
  }

  // 1) convert x_a, x_b, Ws, whh to bf16
  ConvJobs cj;
  cj.src[0] = x_a; cj.dst[0] = xa_bf; cj.n[0] = NN * DD;
  cj.src[1] = x_b; cj.dst[1] = xb_bf; cj.n[1] = NN * DD;
  for (int e = 0; e < 3; ++e) {
    cj.src[2 + e] = Ws[e];  cj.dst[2 + e] = Wsb[e];  cj.n[2 + e] = 16384;
    cj.src[5 + e] = whh[e]; cj.dst[5 + e] = whhb[e]; cj.n[5 + e] = 49152;
  }
  hipLaunchKernelGGL(k_convert, dim3(6250, 8), dim3(256), 0, stream, cj);

  // 2) comb = wih @ Wt per edge type (f32 accum -> bf16)
  CombJobs cb;
  for (int e = 0; e < 3; ++e) { cb.wih[e] = wih[e]; cb.wt[e] = Wt[e]; cb.out[e] = combb[e]; }
  hipLaunchKernelGGL(k_comb, dim3(192, 3), dim3(256), 0, stream, cb);

  float* out_a = (float*)d_out;
  float* out_b = (float*)d_out + (size_t)NN * DD;
  const int ROWT = (NN + 31) / 32;               // 1563
  const int GEMM_BX = (ROWT + 3) / 4;            // 391
  const int EB = (EE + 255) / 256;               // 1954

  const short* srcb[3] = {xa_bf, xb_bf, xb_bf};
  const short* tgtb[3] = {xb_bf, xa_bf, xa_bf};
  float* outp[3] = {out_b, out_a, out_a};
  int mode[3] = {0, 1, 2};

  for (int e = 0; e < 3; ++e) {
    // sx = x_src @ Ws^T
    hipLaunchKernelGGL(k_gemm, dim3(GEMM_BX), dim3(256), 0, stream, srcb[e], Wsb[e], sx_bf);
    // CSR build
    (void)hipMemsetAsync(counts, 0, NN * sizeof(int), stream);
    hipLaunchKernelGGL(k_hist, dim3(EB), dim3(256), 0, stream, edges[e], counts);
    hipLaunchKernelGGL(k_scan, dim3(1), dim3(1024), 0, stream, counts, offs);
    hipLaunchKernelGGL(k_fill, dim3(EB), dim3(256), 0, stream, edges[e], offs, bucket);
    // gather-sum
    hipLaunchKernelGGL(k_agg, dim3((NN + 7) / 8), dim3(256), 0, stream,
                       offs, bucket, (const short*)sx_bf, agg);
    // fused GRU
    GruArgs ga = {tgtb[e], agg, combb[e], whhb[e], bih[e], bhh[e], outp[e], mode[e]};
    hipLaunchKernelGGL(k_gru, dim3(ROWT, 2), dim3(256), 0, stream, ga);
  }
}

// Round 4
// 775.922 us; speedup vs baseline: 7.2672x; 1.1050x over previous
//
#include <hip/hip_runtime.h>
#include <hip/hip_bf16.h>
#include <stdint.h>
#include <math.h>

#define NN 50000
#define DD 128
#define EE 500000

typedef __attribute__((ext_vector_type(8))) short bfx8;   // 8 bf16 = 4 VGPR
typedef __attribute__((ext_vector_type(4))) short bfx4;
typedef __attribute__((ext_vector_type(4))) float f32x4;

static __device__ __forceinline__ short f2bf(float f) {
  union { float f; uint32_t u; } v; v.f = f;
  uint32_t r = (v.u + 0x7fffu + ((v.u >> 16) & 1u)) >> 16;
  return (short)r;
}
static __device__ __forceinline__ float bf2f(short b) {
  union { uint32_t u; float f; } v; v.u = ((uint32_t)(uint16_t)b) << 16;
  return v.f;
}

// A-fragment from global bf16 [rows][128]: lane l -> row row0+(l&15), k k0+(l>>4)*8
static __device__ __forceinline__ bfx8 load_frag_clamp(const short* base, int row0, int k0, int lane) {
  int r = row0 + (lane & 15);
  if (r >= NN) r = NN - 1;
  int k = k0 + ((lane >> 4) << 3);
  return *reinterpret_cast<const bfx8*>(base + (size_t)r * DD + k);
}
// B-fragment from packed weights: [ct][ks][64 lanes][8]
static __device__ __forceinline__ bfx8 load_pk(const short* p, int ct, int ks, int lane) {
  return *reinterpret_cast<const bfx8*>(p + ((((size_t)ct * 4 + ks) * 64 + lane) << 3));
}
// A-fragment from LDS f32 [32][132] -> bf16
static __device__ __forceinline__ bfx8 lds_frag(const float* A, int row0, int ks, int lane) {
  const float* p = A + (size_t)(row0 + (lane & 15)) * 132 + ks * 32 + ((lane >> 4) << 3);
  f32x4 u = *reinterpret_cast<const f32x4*>(p);
  f32x4 v = *reinterpret_cast<const f32x4*>(p + 4);
  bfx8 o;
  o[0]=f2bf(u[0]); o[1]=f2bf(u[1]); o[2]=f2bf(u[2]); o[3]=f2bf(u[3]);
  o[4]=f2bf(v[0]); o[5]=f2bf(v[1]); o[6]=f2bf(v[2]); o[7]=f2bf(v[3]);
  return o;
}

// ---------------- convert fp32 -> bf16 (x_a, x_b) ----------------
struct ConvJobs { const float* src[2]; short* dst[2]; };

__global__ __launch_bounds__(256) void k_convert(ConvJobs jobs) {
  int j = blockIdx.y;
  const float* s = jobs.src[j];
  short* d = jobs.dst[j];
  int i = (blockIdx.x * 256 + threadIdx.x) * 4;
  if (i >= NN * DD) return;
  f32x4 v = *reinterpret_cast<const f32x4*>(s + i);
  bfx4 o;
  o[0]=f2bf(v[0]); o[1]=f2bf(v[1]); o[2]=f2bf(v[2]); o[3]=f2bf(v[3]);
  *reinterpret_cast<bfx4*>(d + i) = o;
}

// ---------------- comb = wih @ Wt  (f32), [384,128] ----------------
struct CombJobs { const float* wih[3]; const float* wt[3]; float* out[3]; };

__global__ __launch_bounds__(256) void k_comb(CombJobs cj) {
  int e = blockIdx.y;
  const float* wih = cj.wih[e];
  const float* wt  = cj.wt[e];
  float* out = cj.out[e];
  int tid = blockIdx.x * 256 + threadIdx.x;   // 49152 total
  int i = tid >> 7, j = tid & 127;
  float acc = 0.f;
  #pragma unroll 4
  for (int k = 0; k < 128; ++k) acc += wih[i * 128 + k] * wt[k * 128 + j];
  out[i * 128 + j] = acc;
}

// ---------------- pack f32 matrix [R][128] into fragment layout bf16 ----------------
struct PackJobs { const float* src[9]; short* dst[9]; int nct[9]; };

__global__ __launch_bounds__(256) void k_pack(PackJobs pj) {
  int j = blockIdx.y;
  int tid = blockIdx.x * 256 + threadIdx.x;
  if (tid >= pj.nct[j] * 256) return;
  int lane = tid & 63, ks = (tid >> 6) & 3, ct = tid >> 8;
  const float* s = pj.src[j] + (size_t)(ct * 16 + (lane & 15)) * 128 + ks * 32 + ((lane >> 4) << 3);
  bfx8 o;
  #pragma unroll
  for (int i = 0; i < 8; ++i) o[i] = f2bf(s[i]);
  *reinterpret_cast<bfx8*>(pj.dst[j] + ((size_t)tid << 3)) = o;
}

// ---------------- CSR build ----------------
__global__ __launch_bounds__(256) void k_hist(const int* __restrict__ edge, int* __restrict__ counts) {
  int tid = blockIdx.x * 256 + threadIdx.x;
  if (tid >= EE) return;
  atomicAdd(&counts[edge[EE + tid]], 1);
}

__global__ __launch_bounds__(1024) void k_scan(const int* __restrict__ counts, int* __restrict__ offs) {
  __shared__ int lds[1024];
  const int C = (NN + 1023) / 1024;   // 49
  int t = threadIdx.x;
  int base = t * C;
  int sum = 0;
  for (int i = 0; i < C; ++i) { int idx = base + i; if (idx < NN) sum += counts[idx]; }
  lds[t] = sum;
  __syncthreads();
  for (int off = 1; off < 1024; off <<= 1) {
    int v = (t >= off) ? lds[t - off] : 0;
    __syncthreads();
    lds[t] += v;
    __syncthreads();
  }
  int excl = lds[t] - sum;
  for (int i = 0; i < C; ++i) {
    int idx = base + i;
    if (idx < NN) { offs[idx] = excl; excl += counts[idx]; }
  }
}

__global__ __launch_bounds__(256) void k_fill(const int* __restrict__ edge,
                                              int* __restrict__ offs,
                                              int* __restrict__ bucket) {
  int tid = blockIdx.x * 256 + threadIdx.x;
  if (tid >= EE) return;
  int t = edge[EE + tid];
  int s = edge[tid];
  int pos = atomicAdd(&offs[t], 1);
  bucket[pos] = s;
}

// ---------------- fused: gather x -> aggX, agg=aggX@Ws^T, GRU, out ----------------
struct FArgs {
  const int* offs; const int* bucket;
  const short* xsrc;   // gather source features bf16 [N][128]
  const short* xt;     // target features bf16 [N][128]
  const short* wsp;    // packed Ws   (8 ct)
  const short* combp;  // packed comb (24 ct)
  const short* whhp;   // packed whh  (24 ct)
  const float* bih; const float* bhh;
  float* out; int mode;
};

__global__ __launch_bounds__(256) void k_fused(FArgs a) {
  __shared__ float aggX[32 * 132];
  __shared__ float aggl[32 * 132];
  const int wave = threadIdx.x >> 6, lane = threadIdx.x & 63;
  const int rbase = blockIdx.x * 32;

  // ---- phase 1: gather-sum raw x rows (8 rows/wave, 8 lanes/row x 16 cols) ----
  {
    int lrow = wave * 8 + (lane >> 3);
    int row = rbase + lrow;
    int c0 = (lane & 7) * 16;
    f32x4 acc[4];
    #pragma unroll
    for (int i = 0; i < 4; ++i) acc[i] = (f32x4)(0.f);
    if (row < NN) {
      int start = row ? a.offs[row - 1] : 0;
      int end = a.offs[row];
      for (int i = start; i < end; ++i) {
        int s = a.bucket[i];
        const short* p = a.xsrc + (size_t)s * DD + c0;
        bfx8 u = *reinterpret_cast<const bfx8*>(p);
        bfx8 v = *reinterpret_cast<const bfx8*>(p + 8);
        #pragma unroll
        for (int j = 0; j < 4; ++j) { acc[0][j] += bf2f(u[j]); acc[1][j] += bf2f(u[4+j]); }
        #pragma unroll
        for (int j = 0; j < 4; ++j) { acc[2][j] += bf2f(v[j]); acc[3][j] += bf2f(v[4+j]); }
      }
      float* dst = aggX + (size_t)lrow * 132 + c0;
      #pragma unroll
      for (int i = 0; i < 4; ++i) *reinterpret_cast<f32x4*>(dst + i * 4) = acc[i];
    }
  }
  __syncthreads();

  // ---- phase 2: agg = aggX @ Ws^T (wave owns cols wave*32..+32) ----
  {
    f32x4 acc[2][2];
    #pragma unroll
    for (int rf = 0; rf < 2; ++rf)
      #pragma unroll
      for (int c = 0; c < 2; ++c) acc[rf][c] = (f32x4)(0.f);
    #pragma unroll
    for (int ks = 0; ks < 4; ++ks) {
      bfx8 a0 = lds_frag(aggX, 0, ks, lane);
      bfx8 a1 = lds_frag(aggX, 16, ks, lane);
      #pragma unroll
      for (int c = 0; c < 2; ++c) {
        bfx8 b = load_pk(a.wsp, wave * 2 + c, ks, lane);
        acc[0][c] = __builtin_amdgcn_mfma_f32_16x16x32_bf16(a0, b, acc[0][c], 0, 0, 0);
        acc[1][c] = __builtin_amdgcn_mfma_f32_16x16x32_bf16(a1, b, acc[1][c], 0, 0, 0);
      }
    }
    const int lq = (lane >> 4) << 2;
    #pragma unroll
    for (int rf = 0; rf < 2; ++rf)
      #pragma unroll
      for (int c = 0; c < 2; ++c) {
        int col = wave * 32 + c * 16 + (lane & 15);
        #pragma unroll
        for (int q = 0; q < 4; ++q)
          aggl[(size_t)(rf * 16 + lq + q) * 132 + col] = acc[rf][c][q];
      }
  }
  __syncthreads();

  // ---- phase 3: gi = xt@comb^T, gh = agg@whh^T ----
  f32x4 ai[2][2][3], ah[2][2][3];
  #pragma unroll
  for (int rf = 0; rf < 2; ++rf)
    #pragma unroll
    for (int c = 0; c < 2; ++c)
      #pragma unroll
      for (int g = 0; g < 3; ++g) { ai[rf][c][g] = (f32x4)(0.f); ah[rf][c][g] = (f32x4)(0.f); }
  #pragma unroll
  for (int ks = 0; ks < 4; ++ks) {
    bfx8 x0 = load_frag_clamp(a.xt, rbase,      ks * 32, lane);
    bfx8 x1 = load_frag_clamp(a.xt, rbase + 16, ks * 32, lane);
    bfx8 g0 = lds_frag(aggl, 0, ks, lane);
    bfx8 g1 = lds_frag(aggl, 16, ks, lane);
    #pragma unroll
    for (int g = 0; g < 3; ++g)
      #pragma unroll
      for (int c = 0; c < 2; ++c) {
        int ct = g * 8 + wave * 2 + c;
        bfx8 bi = load_pk(a.combp, ct, ks, lane);
        bfx8 bh = load_pk(a.whhp,  ct, ks, lane);
        ai[0][c][g] = __builtin_amdgcn_mfma_f32_16x16x32_bf16(x0, bi, ai[0][c][g], 0, 0, 0);
        ai[1][c][g] = __builtin_amdgcn_mfma_f32_16x16x32_bf16(x1, bi, ai[1][c][g], 0, 0, 0);
        ah[0][c][g] = __builtin_amdgcn_mfma_f32_16x16x32_bf16(g0, bh, ah[0][c][g], 0, 0, 0);
        ah[1][c][g] = __builtin_amdgcn_mfma_f32_16x16x32_bf16(g1, bh, ah[1][c][g], 0, 0, 0);
      }
  }

  // ---- epilogue: gates + output ----
  const int lq = (lane >> 4) << 2;
  #pragma unroll
  for (int c = 0; c < 2; ++c) {
    int col = wave * 32 + c * 16 + (lane & 15);
    float bir = a.bih[col], biz = a.bih[128 + col], bin = a.bih[256 + col];
    float bhr = a.bhh[col], bhz = a.bhh[128 + col], bhn = a.bhh[256 + col];
    #pragma unroll
    for (int rf = 0; rf < 2; ++rf)
      #pragma unroll
      for (int q = 0; q < 4; ++q) {
        int lrow = rf * 16 + lq + q;
        int r = rbase + lrow;
        if (r >= NN) continue;
        float ir = ai[rf][c][0][q] + bir, iz = ai[rf][c][1][q] + biz, in = ai[rf][c][2][q] + bin;
        float hr = ah[rf][c][0][q] + bhr, hz = ah[rf][c][1][q] + bhz, hn = ah[rf][c][2][q] + bhn;
        float rr = 1.f / (1.f + expf(-(ir + hr)));
        float zz = 1.f / (1.f + expf(-(iz + hz)));
        float nn = tanhf(in + rr * hn);
        float h  = aggl[(size_t)lrow * 132 + col];
        float res = (1.f - zz) * nn + zz * h;
        size_t o = (size_t)r * DD + col;
        if (a.mode == 0)      a.out[o] = fmaxf(res, 0.f);
        else if (a.mode == 1) a.out[o] = res;
        else                  a.out[o] = fmaxf((a.out[o] + res) * 0.5f, 0.f);
      }
  }
}

extern "C" void kernel_launch(void* const* d_in, const int* in_sizes, int n_in,
                              void* d_out, int out_size, void* d_ws, size_t ws_size,
                              hipStream_t stream) {
  const float* x_a = (const float*)d_in[0];
  const float* x_b = (const float*)d_in[1];
  const int* edges[3] = {(const int*)d_in[2], (const int*)d_in[3], (const int*)d_in[4]};
  const float *Ws[3], *Wt[3], *wih[3], *whh[3], *bih[3], *bhh[3];
  for (int e = 0; e < 3; ++e) {
    int b = 5 + e * 6;
    Ws[e]  = (const float*)d_in[b + 0];
    Wt[e]  = (const float*)d_in[b + 1];
    wih[e] = (const float*)d_in[b + 2];
    whh[e] = (const float*)d_in[b + 3];
    bih[e] = (const float*)d_in[b + 4];
    bhh[e] = (const float*)d_in[b + 5];
  }

  // workspace layout (~30 MB)
  char* ws = (char*)d_ws;
  short* xa_bf   = (short*)ws;                       // 12.8 MB
  short* xb_bf   = (short*)(ws + 12800000);          // 12.8 MB
  int*   counts  = (int*)(ws + 25600000);            // 200 KB
  int*   offs    = (int*)(ws + 25800000);            // 200 KB
  int*   bucket  = (int*)(ws + 26000000);            // 2 MB
  float* comb_f32= (float*)(ws + 28000000);          // 3 x 192 KB
  short* pk      = (short*)(ws + 28600000);          // 3 x 224 KB
  float* combf[3]; short *wsp[3], *combp[3], *whhp[3];
  for (int e = 0; e < 3; ++e) {
    combf[e] = comb_f32 + (size_t)e * 49152;
    short* base = pk + (size_t)e * 114688;           // 32KB+96KB+96KB = 224KB in shorts
    wsp[e] = base; combp[e] = base + 16384; whhp[e] = base + 65536;
  }

  // 1) convert x_a, x_b
  ConvJobs cj;
  cj.src[0] = x_a; cj.dst[0] = xa_bf;
  cj.src[1] = x_b; cj.dst[1] = xb_bf;
  hipLaunchKernelGGL(k_convert, dim3(6250, 2), dim3(256), 0, stream, cj);

  // 2) comb = wih @ Wt (f32)
  CombJobs cb;
  for (int e = 0; e < 3; ++e) { cb.wih[e] = wih[e]; cb.wt[e] = Wt[e]; cb.out[e] = combf[e]; }
  hipLaunchKernelGGL(k_comb, dim3(192, 3), dim3(256), 0, stream, cb);

  // 3) pack Ws (from input f32), comb, whh into fragment layout
  PackJobs pj;
  for (int e = 0; e < 3; ++e) {
    pj.src[e]     = Ws[e];     pj.dst[e]     = wsp[e];   pj.nct[e]     = 8;
    pj.src[3 + e] = combf[e];  pj.dst[3 + e] = combp[e]; pj.nct[3 + e] = 24;
    pj.src[6 + e] = whh[e];    pj.dst[6 + e] = whhp[e];  pj.nct[6 + e] = 24;
  }
  hipLaunchKernelGGL(k_pack, dim3(24, 9), dim3(256), 0, stream, pj);

  float* out_a = (float*)d_out;
  float* out_b = (float*)d_out + (size_t)NN * DD;
  const int ROWT = (NN + 31) / 32;               // 1563
  const int EB = (EE + 255) / 256;               // 1954

  const short* srcb[3] = {xa_bf, xb_bf, xb_bf};
  const short* tgtb[3] = {xb_bf, xa_bf, xa_bf};
  float* outp[3] = {out_b, out_a, out_a};
  int mode[3] = {0, 1, 2};

  for (int e = 0; e < 3; ++e) {
    (void)hipMemsetAsync(counts, 0, NN * sizeof(int), stream);
    hipLaunchKernelGGL(k_hist, dim3(EB), dim3(256), 0, stream, edges[e], counts);
    hipLaunchKernelGGL(k_scan, dim3(1), dim3(1024), 0, stream, counts, offs);
    hipLaunchKernelGGL(k_fill, dim3(EB), dim3(256), 0, stream, edges[e], offs, bucket);
    FArgs fa = {offs, bucket, srcb[e], tgtb[e], wsp[e], combp[e], whhp[e],
                bih[e], bhh[e], outp[e], mode[e]};
    hipLaunchKernelGGL(k_fused, dim3(ROWT), dim3(256), 0, stream, fa);
  }
}